// Round 17
// baseline (161.488 us; speedup 1.0000x reference)
//
#include <hip/hip_runtime.h>
#include <hip/hip_bf16.h>

#define NN 8192
#define DIM 128
#define RPB 8           // rows per fused block
#define KC 256          // k-chunk width in phase B

typedef __attribute__((ext_vector_type(8))) short bf16x8;
typedef __attribute__((ext_vector_type(4))) float f32x4;
typedef __attribute__((ext_vector_type(4))) int i32x4;
typedef __attribute__((ext_vector_type(4))) unsigned int u32x4;
typedef __attribute__((ext_vector_type(4))) unsigned short u16x4;
typedef __attribute__((ext_vector_type(4))) short s16x4;

static __device__ inline unsigned short f2bf(float x) {
    __hip_bfloat16 b = __float2bfloat16(x);
    return *reinterpret_cast<unsigned short*>(&b);
}

struct BSplit { short hi, lo; };
static __device__ inline BSplit bsplit(float x) {
    BSplit r;
    __hip_bfloat16 h = __float2bfloat16(x);
    r.hi = *reinterpret_cast<short*>(&h);
    float rem = x - __bfloat162float(h);
    __hip_bfloat16 l = __float2bfloat16(rem);
    r.lo = *reinterpret_cast<short*>(&l);
    return r;
}

// ---------------------------------------------------------------------------
// K1M: Wh = h@W^T (split-bf16 MFMA, f32-grade), a1 (f32), packed table
// pku[j] = bf16(E1)|bf16(E2)<<16 (leaky branch test a1+a2>=0 equivalent to
// E1 >= exp(-a1)), whbT (bf16, tiled [k>>3][dim][k&7]). 128 blocks x 64 rows.
// ---------------------------------------------------------------------------
__global__ __launch_bounds__(256) void k1m(const float* __restrict__ h,
                                           const float* __restrict__ W,
                                           const float* __restrict__ a,
                                           __hip_bfloat16* __restrict__ whbT,
                                           float* __restrict__ a1g,
                                           unsigned* __restrict__ pku) {
    __shared__ short whi[128 * 132];
    __shared__ short wlo[128 * 132];
    __shared__ short wt[8 * 128 * 8];
    __shared__ float a_sh[256];

    const int tid = threadIdx.x;
    const int wv = tid >> 6, lane = tid & 63;
    const int r0 = blockIdx.x * 64;

    for (int idx = tid; idx < 128 * 128; idx += 256) {
        const int d = idx >> 7, k = idx & 127;
        BSplit s = bsplit(W[idx]);
        whi[d * 132 + k] = s.hi;
        wlo[d * 132 + k] = s.lo;
    }
    a_sh[tid] = a[tid];
    __syncthreads();

    f32x4 acc[8];
    #pragma unroll
    for (int n = 0; n < 8; ++n) acc[n] = (f32x4){0.f, 0.f, 0.f, 0.f};

    const int arow = r0 + wv * 16 + (lane & 15);
    const int ksub = (lane >> 4) * 8;
    const float* hp = h + (size_t)arow * DIM + ksub;

    #pragma unroll
    for (int kk = 0; kk < 128; kk += 32) {
        f32x4 x0 = *(const f32x4*)(hp + kk);
        f32x4 x1 = *(const f32x4*)(hp + kk + 4);
        bf16x8 ah, al;
        {
            BSplit s0 = bsplit(x0.x), s1 = bsplit(x0.y), s2 = bsplit(x0.z), s3 = bsplit(x0.w);
            BSplit s4 = bsplit(x1.x), s5 = bsplit(x1.y), s6 = bsplit(x1.z), s7 = bsplit(x1.w);
            ah[0] = s0.hi; al[0] = s0.lo; ah[1] = s1.hi; al[1] = s1.lo;
            ah[2] = s2.hi; al[2] = s2.lo; ah[3] = s3.hi; al[3] = s3.lo;
            ah[4] = s4.hi; al[4] = s4.lo; ah[5] = s5.hi; al[5] = s5.lo;
            ah[6] = s6.hi; al[6] = s6.lo; ah[7] = s7.hi; al[7] = s7.lo;
        }
        #pragma unroll
        for (int n = 0; n < 8; ++n) {
            const int boff = (n * 16 + (lane & 15)) * 132 + kk + ksub;
            bf16x8 bh = *(const bf16x8*)(whi + boff);
            bf16x8 bl = *(const bf16x8*)(wlo + boff);
            acc[n] = __builtin_amdgcn_mfma_f32_16x16x32_bf16(ah, bh, acc[n], 0, 0, 0);
            acc[n] = __builtin_amdgcn_mfma_f32_16x16x32_bf16(ah, bl, acc[n], 0, 0, 0);
            acc[n] = __builtin_amdgcn_mfma_f32_16x16x32_bf16(al, bh, acc[n], 0, 0, 0);
        }
    }

    float p1[4] = {0.f, 0.f, 0.f, 0.f}, p2[4] = {0.f, 0.f, 0.f, 0.f};
    #pragma unroll
    for (int n = 0; n < 8; ++n) {
        const float av1 = a_sh[n * 16 + (lane & 15)];
        const float av2 = a_sh[128 + n * 16 + (lane & 15)];
        #pragma unroll
        for (int q = 0; q < 4; ++q) {
            p1[q] += acc[n][q] * av1;
            p2[q] += acc[n][q] * av2;
        }
    }
    #pragma unroll
    for (int o = 8; o >= 1; o >>= 1) {
        #pragma unroll
        for (int q = 0; q < 4; ++q) {
            p1[q] += __shfl_xor(p1[q], o, 64);
            p2[q] += __shfl_xor(p2[q], o, 64);
        }
    }
    if ((lane & 15) == 0) {
        #pragma unroll
        for (int q = 0; q < 4; ++q) {
            const int row = r0 + wv * 16 + (lane >> 4) * 4 + q;
            a1g[row] = p1[q];
            const float E1v = expf(p2[q]);
            const float E2v = expf(0.2f * p2[q]);
            pku[row] = (unsigned)f2bf(E1v) | ((unsigned)f2bf(E2v) << 16);
        }
    }

    #pragma unroll
    for (int n = 0; n < 8; ++n) {
        #pragma unroll
        for (int q = 0; q < 4; ++q) {
            const int kloc = wv * 16 + (lane >> 4) * 4 + q;
            const int d = n * 16 + (lane & 15);
            wt[(kloc >> 3) * 1024 + d * 8 + (kloc & 7)] = (short)f2bf(acc[n][q]);
        }
    }
    __syncthreads();
    short* dst = reinterpret_cast<short*>(whbT) + ((size_t)r0 << 7);
    for (int idx = tid * 4; idx < 8192; idx += 1024)
        *(s16x4*)(dst + idx) = *(const s16x4*)(wt + idx);
}

// ---------------------------------------------------------------------------
// ballot group: 256 cols -> 8 LDS words + masked sums.
// word layout per 256-col group: word (2 halves x 4 comps) = ((j>>7)&1)*4 +
// (j&3), bit (j>>2)&31  (matches phase-B extraction).
// ---------------------------------------------------------------------------
static __device__ inline void sa_group(const i32x4 v, const u32x4 tb,
                                       const float T, const int lane,
                                       float& s1, float& s2,
                                       unsigned* bgrp) {
    unsigned long long m0 = __ballot(v.x != 0);
    unsigned long long m1 = __ballot(v.y != 0);
    unsigned long long m2 = __ballot(v.z != 0);
    unsigned long long m3 = __ballot(v.w != 0);
    if (lane == 0) {
        u32x4 w;
        w.x = (unsigned)m0; w.y = (unsigned)m1;
        w.z = (unsigned)m2; w.w = (unsigned)m3;
        *(u32x4*)(bgrp) = w;
    } else if (lane == 32) {
        u32x4 w;
        w.x = (unsigned)(m0 >> 32); w.y = (unsigned)(m1 >> 32);
        w.z = (unsigned)(m2 >> 32); w.w = (unsigned)(m3 >> 32);
        *(u32x4*)(bgrp + 4) = w;
    }
    float e1, e2; bool px;
    e1 = __uint_as_float(tb.x << 16); e2 = __uint_as_float(tb.x & 0xffff0000u);
    px = (e1 >= T);
    s1 += (v.x && px) ? e1 : 0.f;  s2 += (v.x && !px) ? e2 : 0.f;
    e1 = __uint_as_float(tb.y << 16); e2 = __uint_as_float(tb.y & 0xffff0000u);
    px = (e1 >= T);
    s1 += (v.y && px) ? e1 : 0.f;  s2 += (v.y && !px) ? e2 : 0.f;
    e1 = __uint_as_float(tb.z << 16); e2 = __uint_as_float(tb.z & 0xffff0000u);
    px = (e1 >= T);
    s1 += (v.z && px) ? e1 : 0.f;  s2 += (v.z && !px) ? e2 : 0.f;
    e1 = __uint_as_float(tb.w << 16); e2 = __uint_as_float(tb.w & 0xffff0000u);
    px = (e1 >= T);
    s1 += (v.w && px) ? e1 : 0.f;  s2 += (v.w && !px) ? e2 : 0.f;
}

// ---------------------------------------------------------------------------
// FS: fully fused per-8-row block. grid 1024 x 512 thr -> 4 blocks/CU,
// 32 waves/CU (max). LDS ~25 KB.
// Phase A (1 row/wave): stream adj NT, bitmask -> LDS (1 KB/row, no global
// round-trip), masked sums -> c1/c2/T.
// Phase B (wave = row): per 256-col chunk, alpha = f(bm,pku) -> one 1-KB
// contiguous NT store/wave + bf16 LDS stage (dbuf); then 16x16 MFMA
// (rows 8-15 zero-padded) accumulating out over full K. No part/k5.
// ---------------------------------------------------------------------------
__global__ __launch_bounds__(512, 8) void fs(const int* __restrict__ adj,
                                             const float* __restrict__ a1g,
                                             const unsigned* __restrict__ pku,
                                             const __hip_bfloat16* __restrict__ whbT,
                                             float* __restrict__ alpha,
                                             float* __restrict__ out) {
    __shared__ unsigned bmL[RPB][256];                   // 8 KB
    __shared__ __hip_bfloat16 abuf[2][16][KC + 8];       // 16.5 KB
    __shared__ float crowL[RPB][4];

    const int tid = threadIdx.x;
    const int wv = tid >> 6, lane = tid & 63;
    const int r0 = blockIdx.x * RPB;

    // zero A-frag pad rows 8..15 (read-only thereafter)
    #pragma unroll
    for (int b = 0; b < 2; ++b) {
        unsigned* pz = (unsigned*)&abuf[b][8][0];        // 8*(KC+8) shorts
        for (int idx = tid; idx < 4 * (KC + 8); idx += 512) pz[idx] = 0;
    }

    // ---- phase A ----
    {
        const int gi = r0 + wv;
        const float a1i = a1g[gi];
        const float T = expf(-a1i);
        const int* arow = adj + (size_t)gi * NN;
        float s1 = 0.f, s2 = 0.f;
        for (int it = 0; it < NN / 512; ++it) {
            const int j0 = it * 512 + lane * 4;
            i32x4 v0 = __builtin_nontemporal_load((const i32x4*)(arow + j0));
            i32x4 v1 = __builtin_nontemporal_load((const i32x4*)(arow + j0 + 256));
            u32x4 t0 = *(const u32x4*)(pku + j0);
            u32x4 t1 = *(const u32x4*)(pku + j0 + 256);
            sa_group(v0, t0, T, lane, s1, s2, &bmL[wv][it * 16]);
            sa_group(v1, t1, T, lane, s1, s2, &bmL[wv][it * 16 + 8]);
        }
        #pragma unroll
        for (int o = 32; o >= 1; o >>= 1) {
            s1 += __shfl_xor(s1, o, 64);
            s2 += __shfl_xor(s2, o, 64);
        }
        if (lane == 0) {
            float c1 = 0.f, c2 = 0.f;
            if (s1 + s2 > 0.f) {
                float e1v = expf(a1i);
                float e2v = expf(0.2f * a1i);
                float S = e1v * s1 + e2v * s2;
                c1 = e1v / S;
                c2 = e2v / S;
            }
            crowL[wv][0] = c1; crowL[wv][1] = c2; crowL[wv][2] = T;
        }
    }
    __syncthreads();

    // ---- phase B ----
    const float c1 = crowL[wv][0], c2 = crowL[wv][1], Tb = crowL[wv][2];
    f32x4 acc = (f32x4){0.f, 0.f, 0.f, 0.f};
    const int n0 = wv * 16;
    const short* wb = reinterpret_cast<const short*>(whbT);
    const short* bbase = wb + (size_t)(n0 + (lane & 15)) * 8 + (size_t)(lane >> 4) * 1024;
    float* arow_out = alpha + (size_t)(r0 + wv) * NN;
    const unsigned pbit = lane & 31;

    for (int kc = 0; kc < NN; kc += KC) {
        const int dbuf = (kc >> 8) & 1;
        const int j = kc + lane * 4;
        const int wbw = ((j >> 8) << 3) + (((j >> 7) & 1) << 2);
        u32x4 tb = *(const u32x4*)(pku + j);
        u32x4 w4 = *(const u32x4*)(&bmL[wv][wbw]);
        float e1c[4], e2c[4];
        e1c[0] = __uint_as_float(tb.x << 16); e2c[0] = __uint_as_float(tb.x & 0xffff0000u);
        e1c[1] = __uint_as_float(tb.y << 16); e2c[1] = __uint_as_float(tb.y & 0xffff0000u);
        e1c[2] = __uint_as_float(tb.z << 16); e2c[2] = __uint_as_float(tb.z & 0xffff0000u);
        e1c[3] = __uint_as_float(tb.w << 16); e2c[3] = __uint_as_float(tb.w & 0xffff0000u);
        f32x4 al;
        al.x = ((w4.x >> pbit) & 1) ? ((e1c[0] >= Tb) ? c1 * e1c[0] : c2 * e2c[0]) : 0.f;
        al.y = ((w4.y >> pbit) & 1) ? ((e1c[1] >= Tb) ? c1 * e1c[1] : c2 * e2c[1]) : 0.f;
        al.z = ((w4.z >> pbit) & 1) ? ((e1c[2] >= Tb) ? c1 * e1c[2] : c2 * e2c[2]) : 0.f;
        al.w = ((w4.w >> pbit) & 1) ? ((e1c[3] >= Tb) ? c1 * e1c[3] : c2 * e2c[3]) : 0.f;
        __builtin_nontemporal_store(al, (f32x4*)(arow_out + j));
        u16x4 ub4;
        ub4.x = f2bf(al.x); ub4.y = f2bf(al.y); ub4.z = f2bf(al.z); ub4.w = f2bf(al.w);
        *(u16x4*)(&abuf[dbuf][wv][lane * 4]) = ub4;
        __syncthreads();
        #pragma unroll
        for (int kk = 0; kk < KC; kk += 32) {
            bf16x8 bf = *(const bf16x8*)(bbase + (size_t)((kc + kk) >> 3) * 1024);
            bf16x8 af = *(const bf16x8*)(&abuf[dbuf][lane & 15][kk + 8 * (lane >> 4)]);
            acc = __builtin_amdgcn_mfma_f32_16x16x32_bf16(af, bf, acc, 0, 0, 0);
        }
    }

    // out: rows 0..7 valid (A rows 8-15 were zero-padding)
    const int rl = (lane >> 4) * 4;
    if (rl < RPB) {
        #pragma unroll
        for (int q = 0; q < 4; ++q)
            out[(size_t)(r0 + rl + q) * DIM + n0 + (lane & 15)] = acc[q];
    }
}

// ---------------------------------------------------------------------------
extern "C" void kernel_launch(void* const* d_in, const int* in_sizes, int n_in,
                              void* d_out, int out_size, void* d_ws, size_t ws_size,
                              hipStream_t stream) {
    const float* h   = (const float*)d_in[0];
    const int*   adj = (const int*)d_in[1];
    const float* W   = (const float*)d_in[2];
    const float* a   = (const float*)d_in[3];

    float* out   = (float*)d_out;
    float* alpha = out + (size_t)NN * DIM;

    char* ws = (char*)d_ws;
    __hip_bfloat16* whbT = (__hip_bfloat16*)(ws);          // 2 MB
    float* a1g    = (float*)(ws + 0x200000);               // 32 KB
    unsigned* pku = (unsigned*)(ws + 0x208000);            // 32 KB

    k1m<<<NN / 64, 256, 0, stream>>>(h, W, a, whbT, a1g, pku);
    fs<<<NN / RPB, 512, 0, stream>>>(adj, a1g, pku, whbT, alpha, out);
}

// Round 18
// 153.700 us; speedup vs baseline: 1.0507x; 1.0507x over previous
//
#include <hip/hip_runtime.h>
#include <hip/hip_bf16.h>

#define NN 8192
#define DIM 128
#define RPB 8           // rows per fused block
#define KC 256          // k-chunk width in phase B

typedef __attribute__((ext_vector_type(8))) short bf16x8;
typedef __attribute__((ext_vector_type(4))) float f32x4;
typedef __attribute__((ext_vector_type(4))) int i32x4;
typedef __attribute__((ext_vector_type(4))) unsigned int u32x4;
typedef __attribute__((ext_vector_type(4))) unsigned short u16x4;
typedef __attribute__((ext_vector_type(4))) short s16x4;

static __device__ inline unsigned short f2bf(float x) {
    __hip_bfloat16 b = __float2bfloat16(x);
    return *reinterpret_cast<unsigned short*>(&b);
}

struct BSplit { short hi, lo; };
static __device__ inline BSplit bsplit(float x) {
    BSplit r;
    __hip_bfloat16 h = __float2bfloat16(x);
    r.hi = *reinterpret_cast<short*>(&h);
    float rem = x - __bfloat162float(h);
    __hip_bfloat16 l = __float2bfloat16(rem);
    r.lo = *reinterpret_cast<short*>(&l);
    return r;
}

// ---------------------------------------------------------------------------
// K1M: Wh = h@W^T (split-bf16 MFMA, f32-grade), a1 (f32), packed table
// pku[j] = bf16(E1)|bf16(E2)<<16 (leaky branch test a1+a2>=0 equivalent to
// E1 >= exp(-a1)), whbT (bf16, tiled [k>>3][dim][k&7]). 128 blocks x 64 rows.
// ---------------------------------------------------------------------------
__global__ __launch_bounds__(256) void k1m(const float* __restrict__ h,
                                           const float* __restrict__ W,
                                           const float* __restrict__ a,
                                           __hip_bfloat16* __restrict__ whbT,
                                           float* __restrict__ a1g,
                                           unsigned* __restrict__ pku) {
    __shared__ short whi[128 * 132];
    __shared__ short wlo[128 * 132];
    __shared__ short wt[8 * 128 * 8];
    __shared__ float a_sh[256];

    const int tid = threadIdx.x;
    const int wv = tid >> 6, lane = tid & 63;
    const int r0 = blockIdx.x * 64;

    for (int idx = tid; idx < 128 * 128; idx += 256) {
        const int d = idx >> 7, k = idx & 127;
        BSplit s = bsplit(W[idx]);
        whi[d * 132 + k] = s.hi;
        wlo[d * 132 + k] = s.lo;
    }
    a_sh[tid] = a[tid];
    __syncthreads();

    f32x4 acc[8];
    #pragma unroll
    for (int n = 0; n < 8; ++n) acc[n] = (f32x4){0.f, 0.f, 0.f, 0.f};

    const int arow = r0 + wv * 16 + (lane & 15);
    const int ksub = (lane >> 4) * 8;
    const float* hp = h + (size_t)arow * DIM + ksub;

    #pragma unroll
    for (int kk = 0; kk < 128; kk += 32) {
        f32x4 x0 = *(const f32x4*)(hp + kk);
        f32x4 x1 = *(const f32x4*)(hp + kk + 4);
        bf16x8 ah, al;
        {
            BSplit s0 = bsplit(x0.x), s1 = bsplit(x0.y), s2 = bsplit(x0.z), s3 = bsplit(x0.w);
            BSplit s4 = bsplit(x1.x), s5 = bsplit(x1.y), s6 = bsplit(x1.z), s7 = bsplit(x1.w);
            ah[0] = s0.hi; al[0] = s0.lo; ah[1] = s1.hi; al[1] = s1.lo;
            ah[2] = s2.hi; al[2] = s2.lo; ah[3] = s3.hi; al[3] = s3.lo;
            ah[4] = s4.hi; al[4] = s4.lo; ah[5] = s5.hi; al[5] = s5.lo;
            ah[6] = s6.hi; al[6] = s6.lo; ah[7] = s7.hi; al[7] = s7.lo;
        }
        #pragma unroll
        for (int n = 0; n < 8; ++n) {
            const int boff = (n * 16 + (lane & 15)) * 132 + kk + ksub;
            bf16x8 bh = *(const bf16x8*)(whi + boff);
            bf16x8 bl = *(const bf16x8*)(wlo + boff);
            acc[n] = __builtin_amdgcn_mfma_f32_16x16x32_bf16(ah, bh, acc[n], 0, 0, 0);
            acc[n] = __builtin_amdgcn_mfma_f32_16x16x32_bf16(ah, bl, acc[n], 0, 0, 0);
            acc[n] = __builtin_amdgcn_mfma_f32_16x16x32_bf16(al, bh, acc[n], 0, 0, 0);
        }
    }

    float p1[4] = {0.f, 0.f, 0.f, 0.f}, p2[4] = {0.f, 0.f, 0.f, 0.f};
    #pragma unroll
    for (int n = 0; n < 8; ++n) {
        const float av1 = a_sh[n * 16 + (lane & 15)];
        const float av2 = a_sh[128 + n * 16 + (lane & 15)];
        #pragma unroll
        for (int q = 0; q < 4; ++q) {
            p1[q] += acc[n][q] * av1;
            p2[q] += acc[n][q] * av2;
        }
    }
    #pragma unroll
    for (int o = 8; o >= 1; o >>= 1) {
        #pragma unroll
        for (int q = 0; q < 4; ++q) {
            p1[q] += __shfl_xor(p1[q], o, 64);
            p2[q] += __shfl_xor(p2[q], o, 64);
        }
    }
    if ((lane & 15) == 0) {
        #pragma unroll
        for (int q = 0; q < 4; ++q) {
            const int row = r0 + wv * 16 + (lane >> 4) * 4 + q;
            a1g[row] = p1[q];
            const float E1v = expf(p2[q]);
            const float E2v = expf(0.2f * p2[q]);
            pku[row] = (unsigned)f2bf(E1v) | ((unsigned)f2bf(E2v) << 16);
        }
    }

    #pragma unroll
    for (int n = 0; n < 8; ++n) {
        #pragma unroll
        for (int q = 0; q < 4; ++q) {
            const int kloc = wv * 16 + (lane >> 4) * 4 + q;
            const int d = n * 16 + (lane & 15);
            wt[(kloc >> 3) * 1024 + d * 8 + (kloc & 7)] = (short)f2bf(acc[n][q]);
        }
    }
    __syncthreads();
    short* dst = reinterpret_cast<short*>(whbT) + ((size_t)r0 << 7);
    for (int idx = tid * 4; idx < 8192; idx += 1024)
        *(s16x4*)(dst + idx) = *(const s16x4*)(wt + idx);
}

// ---------------------------------------------------------------------------
// ballot group: 256 cols -> 8 LDS words + masked sums. Word layout per
// 256-col group: word ((j>>7)&1)*4 + (j&3), bit (j>>2)&31.
// ---------------------------------------------------------------------------
static __device__ inline void sa_group(const i32x4 v, const u32x4 tb,
                                       const float T, const int lane,
                                       float& s1, float& s2,
                                       unsigned* bgrp) {
    unsigned long long m0 = __ballot(v.x != 0);
    unsigned long long m1 = __ballot(v.y != 0);
    unsigned long long m2 = __ballot(v.z != 0);
    unsigned long long m3 = __ballot(v.w != 0);
    if (lane == 0) {
        u32x4 w;
        w.x = (unsigned)m0; w.y = (unsigned)m1;
        w.z = (unsigned)m2; w.w = (unsigned)m3;
        *(u32x4*)(bgrp) = w;
    } else if (lane == 32) {
        u32x4 w;
        w.x = (unsigned)(m0 >> 32); w.y = (unsigned)(m1 >> 32);
        w.z = (unsigned)(m2 >> 32); w.w = (unsigned)(m3 >> 32);
        *(u32x4*)(bgrp + 4) = w;
    }
    float e1, e2; bool px;
    e1 = __uint_as_float(tb.x << 16); e2 = __uint_as_float(tb.x & 0xffff0000u);
    px = (e1 >= T);
    s1 += (v.x && px) ? e1 : 0.f;  s2 += (v.x && !px) ? e2 : 0.f;
    e1 = __uint_as_float(tb.y << 16); e2 = __uint_as_float(tb.y & 0xffff0000u);
    px = (e1 >= T);
    s1 += (v.y && px) ? e1 : 0.f;  s2 += (v.y && !px) ? e2 : 0.f;
    e1 = __uint_as_float(tb.z << 16); e2 = __uint_as_float(tb.z & 0xffff0000u);
    px = (e1 >= T);
    s1 += (v.z && px) ? e1 : 0.f;  s2 += (v.z && !px) ? e2 : 0.f;
    e1 = __uint_as_float(tb.w << 16); e2 = __uint_as_float(tb.w & 0xffff0000u);
    px = (e1 >= T);
    s1 += (v.w && px) ? e1 : 0.f;  s2 += (v.w && !px) ? e2 : 0.f;
}

// ---------------------------------------------------------------------------
// FS v2: fused per-8-row block, 256 threads (4 waves), grid 1024
// -> 6 blocks/CU (25.5 KB LDS), 24 waves/CU, 4-wave barrier scope.
// Phase A: 2 rows/wave adj scan -> bitmask in LDS + softmax coeffs.
// Phase B: per 256-col chunk each wave writes alpha for its 2 rows (1-KB
// contiguous NT stores) + stages bf16; 16 MFMA/wave/chunk (2 col-tiles of
// 32 dims, rows 8-15 zero-padded). out accumulated over full K in regs.
// ---------------------------------------------------------------------------
__global__ __launch_bounds__(256, 6) void fs(const int* __restrict__ adj,
                                             const float* __restrict__ a1g,
                                             const unsigned* __restrict__ pku,
                                             const __hip_bfloat16* __restrict__ whbT,
                                             float* __restrict__ alpha,
                                             float* __restrict__ out) {
    __shared__ unsigned bmL[RPB][256];                   // 8 KB
    __shared__ __hip_bfloat16 abuf[2][16][KC + 8];       // 16.5 KB
    __shared__ float crowL[RPB][4];

    const int tid = threadIdx.x;
    const int wv = tid >> 6, lane = tid & 63;            // wv in 0..3
    const int r0 = blockIdx.x * RPB;

    // zero A-frag pad rows 8..15
    #pragma unroll
    for (int b = 0; b < 2; ++b) {
        unsigned* pz = (unsigned*)&abuf[b][8][0];
        for (int idx = tid; idx < 4 * (KC + 8); idx += 256) pz[idx] = 0;
    }

    // ---- phase A: 2 rows per wave ----
    #pragma unroll
    for (int rr = 0; rr < 2; ++rr) {
        const int r = wv * 2 + rr;
        const int gi = r0 + r;
        const float a1i = a1g[gi];
        const float T = expf(-a1i);
        const int* arow = adj + (size_t)gi * NN;
        float s1 = 0.f, s2 = 0.f;
        for (int it = 0; it < NN / 512; ++it) {
            const int j0 = it * 512 + lane * 4;
            i32x4 v0 = __builtin_nontemporal_load((const i32x4*)(arow + j0));
            i32x4 v1 = __builtin_nontemporal_load((const i32x4*)(arow + j0 + 256));
            u32x4 t0 = *(const u32x4*)(pku + j0);
            u32x4 t1 = *(const u32x4*)(pku + j0 + 256);
            sa_group(v0, t0, T, lane, s1, s2, &bmL[r][it * 16]);
            sa_group(v1, t1, T, lane, s1, s2, &bmL[r][it * 16 + 8]);
        }
        #pragma unroll
        for (int o = 32; o >= 1; o >>= 1) {
            s1 += __shfl_xor(s1, o, 64);
            s2 += __shfl_xor(s2, o, 64);
        }
        if (lane == 0) {
            float c1 = 0.f, c2 = 0.f;
            if (s1 + s2 > 0.f) {
                float e1v = expf(a1i);
                float e2v = expf(0.2f * a1i);
                float S = e1v * s1 + e2v * s2;
                c1 = e1v / S;
                c2 = e2v / S;
            }
            crowL[r][0] = c1; crowL[r][1] = c2; crowL[r][2] = T;
        }
    }
    __syncthreads();

    // ---- phase B ----
    float c1r[2], c2r[2], Tr[2];
    #pragma unroll
    for (int rr = 0; rr < 2; ++rr) {
        const int r = wv * 2 + rr;
        c1r[rr] = crowL[r][0]; c2r[rr] = crowL[r][1]; Tr[rr] = crowL[r][2];
    }
    f32x4 acc0 = (f32x4){0.f, 0.f, 0.f, 0.f};
    f32x4 acc1 = (f32x4){0.f, 0.f, 0.f, 0.f};
    const int n0 = wv * 32;                              // 32 dims per wave
    const short* wb = reinterpret_cast<const short*>(whbT);
    const short* bbase = wb + (size_t)(n0 + (lane & 15)) * 8 + (size_t)(lane >> 4) * 1024;
    const unsigned pbit = lane & 31;

    for (int kc = 0; kc < NN; kc += KC) {
        const int dbuf = (kc >> 8) & 1;
        const int j = kc + lane * 4;
        const int wbw = ((j >> 8) << 3) + (((j >> 7) & 1) << 2);
        u32x4 tb = *(const u32x4*)(pku + j);
        float e1c[4], e2c[4];
        e1c[0] = __uint_as_float(tb.x << 16); e2c[0] = __uint_as_float(tb.x & 0xffff0000u);
        e1c[1] = __uint_as_float(tb.y << 16); e2c[1] = __uint_as_float(tb.y & 0xffff0000u);
        e1c[2] = __uint_as_float(tb.z << 16); e2c[2] = __uint_as_float(tb.z & 0xffff0000u);
        e1c[3] = __uint_as_float(tb.w << 16); e2c[3] = __uint_as_float(tb.w & 0xffff0000u);
        #pragma unroll
        for (int rr = 0; rr < 2; ++rr) {
            const int r = wv * 2 + rr;
            u32x4 w4 = *(const u32x4*)(&bmL[r][wbw]);
            const float c1 = c1r[rr], c2 = c2r[rr], T = Tr[rr];
            f32x4 al;
            al.x = ((w4.x >> pbit) & 1) ? ((e1c[0] >= T) ? c1 * e1c[0] : c2 * e2c[0]) : 0.f;
            al.y = ((w4.y >> pbit) & 1) ? ((e1c[1] >= T) ? c1 * e1c[1] : c2 * e2c[1]) : 0.f;
            al.z = ((w4.z >> pbit) & 1) ? ((e1c[2] >= T) ? c1 * e1c[2] : c2 * e2c[2]) : 0.f;
            al.w = ((w4.w >> pbit) & 1) ? ((e1c[3] >= T) ? c1 * e1c[3] : c2 * e2c[3]) : 0.f;
            __builtin_nontemporal_store(al, (f32x4*)(alpha + (size_t)(r0 + r) * NN + j));
            u16x4 ub4;
            ub4.x = f2bf(al.x); ub4.y = f2bf(al.y); ub4.z = f2bf(al.z); ub4.w = f2bf(al.w);
            *(u16x4*)(&abuf[dbuf][r][lane * 4]) = ub4;
        }
        __syncthreads();
        #pragma unroll
        for (int kk = 0; kk < KC; kk += 32) {
            const short* bp = bbase + (size_t)((kc + kk) >> 3) * 1024;
            bf16x8 b0 = *(const bf16x8*)(bp);
            bf16x8 b1 = *(const bf16x8*)(bp + 128);      // +16 dims
            bf16x8 af = *(const bf16x8*)(&abuf[dbuf][lane & 15][kk + 8 * (lane >> 4)]);
            acc0 = __builtin_amdgcn_mfma_f32_16x16x32_bf16(af, b0, acc0, 0, 0, 0);
            acc1 = __builtin_amdgcn_mfma_f32_16x16x32_bf16(af, b1, acc1, 0, 0, 0);
        }
    }

    // out: rows 0..7 valid (A rows 8-15 were zero-padding)
    const int rl = (lane >> 4) * 4;
    if (rl < RPB) {
        #pragma unroll
        for (int q = 0; q < 4; ++q) {
            out[(size_t)(r0 + rl + q) * DIM + n0 + (lane & 15)] = acc0[q];
            out[(size_t)(r0 + rl + q) * DIM + n0 + 16 + (lane & 15)] = acc1[q];
        }
    }
}

// ---------------------------------------------------------------------------
extern "C" void kernel_launch(void* const* d_in, const int* in_sizes, int n_in,
                              void* d_out, int out_size, void* d_ws, size_t ws_size,
                              hipStream_t stream) {
    const float* h   = (const float*)d_in[0];
    const int*   adj = (const int*)d_in[1];
    const float* W   = (const float*)d_in[2];
    const float* a   = (const float*)d_in[3];

    float* out   = (float*)d_out;
    float* alpha = out + (size_t)NN * DIM;

    char* ws = (char*)d_ws;
    __hip_bfloat16* whbT = (__hip_bfloat16*)(ws);          // 2 MB
    float* a1g    = (float*)(ws + 0x200000);               // 32 KB
    unsigned* pku = (unsigned*)(ws + 0x208000);            // 32 KB

    k1m<<<NN / 64, 256, 0, stream>>>(h, W, a, whbT, a1g, pku);
    fs<<<NN / RPB, 256, 0, stream>>>(adj, a1g, pku, whbT, alpha, out);
}